// Round 3
// baseline (178.896 us; speedup 1.0000x reference)
//
#include <hip/hip_runtime.h>
#include <cstdint>
#include <cstddef>

typedef unsigned short u16;
typedef unsigned int u32;
typedef unsigned char u8;

using bfx8 = __attribute__((ext_vector_type(8))) __bf16;
using floatx16 = __attribute__((ext_vector_type(16))) float;

// B=8, S=1024, D=768, H=12, DH=64
static constexpr int kS = 1024;
static constexpr int kD = 768;
static constexpr int kH = 12;
static constexpr int kDH = 64;
#define SCALE 0.036084391824351614f  // 1/sqrt(768)

__device__ __forceinline__ u16 f2bf(float f) {
    u32 u = __float_as_uint(f);
    return (u16)((u + 0x7fffu + ((u >> 16) & 1u)) >> 16);
}

// async global->LDS, 16B per lane. LDS dst = uniform base + lane*16.
__device__ __forceinline__ void gld16(const void* g, void* l) {
    __builtin_amdgcn_global_load_lds(
        (__attribute__((address_space(1))) const u32*)g,
        (__attribute__((address_space(3))) u32*)l, 16, 0, 0);
}

#define VMW(n) asm volatile("s_waitcnt vmcnt(" #n ")" ::: "memory")
#define LGKM0 asm volatile("s_waitcnt lgkmcnt(0)" ::: "memory")

// ---------------- kernel 1: fused converts ----------------
// blocks [0,6144): x fp32 -> bf16.  blocks [6144,7872): W (k,n) fp32 -> Wt (n,k) bf16 concat.
__global__ __launch_bounds__(256) void cvt(const float* __restrict__ x, u16* __restrict__ xb,
                                           const float* __restrict__ w0, const float* __restrict__ w1,
                                           const float* __restrict__ w2, u16* __restrict__ wt) {
    __shared__ float t[32][33];
    int bid = blockIdx.x;
    if (bid < 6144) {
        int i = (bid * 256 + threadIdx.x) * 4;
        float4 v = *(const float4*)(x + i);
        u32 lo = (u32)f2bf(v.x) | ((u32)f2bf(v.y) << 16);
        u32 hi = (u32)f2bf(v.z) | ((u32)f2bf(v.w) << 16);
        *(uint2*)(xb + i) = make_uint2(lo, hi);
    } else {
        int idx = bid - 6144;
        int z = idx / 576;
        int rem = idx - z * 576;
        int by = rem / 24, bx = rem - by * 24;
        const float* W = z == 0 ? w0 : (z == 1 ? w1 : w2);
        u16* dst = wt + (size_t)z * kD * kD;
        int k0 = bx * 32, n0 = by * 32;
        int tx = threadIdx.x & 31, ty = threadIdx.x >> 5;  // 32 x 8
#pragma unroll
        for (int j = 0; j < 4; j++)
            t[ty + j * 8][tx] = W[(size_t)(k0 + ty + j * 8) * kD + n0 + tx];
        __syncthreads();
#pragma unroll
        for (int j = 0; j < 4; j++)
            dst[(size_t)(n0 + ty + j * 8) * kD + k0 + tx] = f2bf(t[tx][ty + j * 8]);
    }
}

// ---------------- kernel 2: fused QKV projection GEMM, 256x256 tile, 8-wave, counted-vmcnt ----------------
// C[8192 x 2304] = Xb[8192 x 768] @ [Wq|Wk|Wv]^T-rows + bias.
// T3+T4: 4 mi-phases per K-tile; per phase {ds_read frags, stage 2 units of next tile,
// sched_barrier, [counted vmcnt], s_barrier, lgkm drain, setprio(1)+8 MFMA+setprio(0), s_barrier}.
// Staging units (8 KB = 512 lanes x 16B each): A quarters 0..3 (64 rows each), B quarters 0..3.
// Issue order P0:A0,A2  P1:B0,B1  P2:B2,B3  P3:A1,A3.  Consumption next iter: P0 needs B*+A0/A2
// (confirmed by vmcnt(2)+barrier at P3), P2 needs A1/A3 (confirmed by vmcnt(4)+barrier at P1).
// Loads never drain to 0 in the main loop. Last iter stages a garbage tile (ks=768) that stays
// inside the workspace and is never consumed.
// Q gets *SCALE folded in. V stored transposed per-head (b,h,dh,s), s sigma-permuted (bits 2<->3).
__global__ __launch_bounds__(512, 2) void proj(const u16* __restrict__ xb, const u16* __restrict__ wt,
                                               const float* __restrict__ bq, const float* __restrict__ bk,
                                               const float* __restrict__ bvp,
                                               u16* __restrict__ qb, u16* __restrict__ kb, u16* __restrict__ vt) {
    __shared__ u16 As0[256 * 64];
    __shared__ u16 Bs0[256 * 64];
    __shared__ u16 As1[256 * 64];
    __shared__ u16 Bs1[256 * 64];
    // XCD swizzle: nwg=288, 8 XCDs, chunk=36 (bijective).
    int orig = blockIdx.x;
    int wg = (orig & 7) * 36 + (orig >> 3);
    int mt = wg / 9, nt = wg - mt * 9;   // n-fastest within each XCD chunk
    int m0 = mt * 256;
    int t = threadIdx.x;
    int w = t >> 6, lane = t & 63;
    int l31 = lane & 31, hi = lane >> 5;
    int wm = (w & 1) * 128, wn = (w >> 1) * 64;   // per-wave output 128x64
    int rowt = t >> 3;                             // 0..63: row within a 64-row unit
    int ch8 = ((t & 7) ^ (rowt & 7)) * 8;          // swizzled global chunk (u16 offset)
    const u16* Arow = xb + (size_t)m0 * kD;
    const u16* Brow = wt + (size_t)(nt * 256) * kD;
    int swz = l31 & 7;
    int tc[4];
#pragma unroll
    for (int s_ = 0; s_ < 4; s_++) tc[s_] = ((s_ * 2 + hi) ^ swz) * 8;
    floatx16 acc[4][2] = {};
    bfx8 bfr[2][4];

#define STG(DB, SRC, U, KSN) \
    gld16((SRC) + (size_t)(64 * (U) + rowt) * kD + (KSN) + ch8, (DB) + (U) * 4096 + w * 512)

#define PHASE(RA, RB, MI, STAGES, VMN)                                          \
    {                                                                           \
        bfx8 af[4];                                                             \
        const u16* ar_ = (RA) + (wm + (MI) * 32 + l31) * 64;                    \
        _Pragma("unroll")                                                       \
        for (int s_ = 0; s_ < 4; s_++) af[s_] = *(const bfx8*)(ar_ + tc[s_]);   \
        if ((MI) == 0) {                                                        \
            _Pragma("unroll")                                                   \
            for (int ni_ = 0; ni_ < 2; ni_++) {                                 \
                const u16* br_ = (RB) + (wn + ni_ * 32 + l31) * 64;             \
                _Pragma("unroll")                                               \
                for (int s_ = 0; s_ < 4; s_++)                                  \
                    bfr[ni_][s_] = *(const bfx8*)(br_ + tc[s_]);                \
            }                                                                   \
        }                                                                       \
        STAGES;                                                                 \
        __builtin_amdgcn_sched_barrier(0);                                      \
        VMN;                                                                    \
        __builtin_amdgcn_s_barrier();                                           \
        LGKM0;                                                                  \
        __builtin_amdgcn_s_setprio(1);                                          \
        _Pragma("unroll")                                                       \
        for (int s_ = 0; s_ < 4; s_++)                                          \
            _Pragma("unroll")                                                   \
            for (int ni_ = 0; ni_ < 2; ni_++)                                   \
                acc[MI][ni_] = __builtin_amdgcn_mfma_f32_32x32x16_bf16(         \
                    af[s_], bfr[ni_][s_], acc[MI][ni_], 0, 0, 0);               \
        __builtin_amdgcn_s_setprio(0);                                          \
        __builtin_amdgcn_s_barrier();                                           \
    }

#define ITERK(RA, RB, WA, WB, KSN)                                                        \
    PHASE(RA, RB, 0, { STG(WA, Arow, 0, KSN); STG(WA, Arow, 2, KSN); }, )                 \
    PHASE(RA, RB, 1, { STG(WB, Brow, 0, KSN); STG(WB, Brow, 1, KSN); }, VMW(4))           \
    PHASE(RA, RB, 2, { STG(WB, Brow, 2, KSN); STG(WB, Brow, 3, KSN); }, )                 \
    PHASE(RA, RB, 3, { STG(WA, Arow, 1, KSN); STG(WA, Arow, 3, KSN); }, VMW(2))

    // prologue: stage tile 0 fully into buf0, drain, publish
#pragma unroll
    for (int u = 0; u < 4; u++) {
        STG(As0, Arow, u, 0);
        STG(Bs0, Brow, u, 0);
    }
    VMW(0);
    __builtin_amdgcn_s_barrier();

    for (int kp = 0; kp < 6; kp++) {
        int kn1 = kp * 128 + 64;
        int kn2 = kp * 128 + 128;   // kp=5: ks=768 -> garbage tile, memory-safe, never consumed
        ITERK(As0, Bs0, As1, Bs1, kn1)
        ITERK(As1, Bs1, As0, Bs0, kn2)
    }

    // epilogue: C/D layout col=lane&31, row=(reg&3)+8*(reg>>2)+4*(lane>>5)
    int zz = nt / 3;                  // 0=Q 1=K 2=V
    int nl0 = (nt - zz * 3) * 256;
    const float* bias = zz == 0 ? bq : (zz == 1 ? bk : bvp);
    float mul = zz == 0 ? SCALE : 1.0f;
#pragma unroll
    for (int ni = 0; ni < 2; ni++) {
        int nl = nl0 + wn + ni * 32 + l31;
        float bb = bias[nl];
#pragma unroll
        for (int mi = 0; mi < 4; mi++) {
            if (zz < 2) {
                int mbase = m0 + wm + mi * 32 + 4 * hi;
                u16* dst = zz == 0 ? qb : kb;
#pragma unroll
                for (int reg = 0; reg < 16; reg++) {
                    int m = mbase + (reg & 3) + 8 * (reg >> 2);
                    dst[(size_t)m * kD + nl] = f2bf((acc[mi][ni][reg] + bb) * mul);
                }
            } else {
                int hh = nl >> 6, dh = nl & 63;
#pragma unroll
                for (int g = 0; g < 4; g++) {
                    // sigma-permuted store: original s had bit2=hi, bit3=g&1; swap them.
                    int m = (m0 + wm + mi * 32) + 4 * (g & 1) + 8 * hi + 16 * (g >> 1);
                    int bi = m >> 10, s = m & 1023;
                    u32 lo = (u32)f2bf(acc[mi][ni][4 * g + 0] + bb) | ((u32)f2bf(acc[mi][ni][4 * g + 1] + bb) << 16);
                    u32 h2 = (u32)f2bf(acc[mi][ni][4 * g + 2] + bb) | ((u32)f2bf(acc[mi][ni][4 * g + 3] + bb) << 16);
                    *(uint2*)&vt[(((size_t)bi * kH + hh) * kDH + dh) * kS + s] = make_uint2(lo, h2);
                }
            }
        }
    }
#undef STG
#undef PHASE
#undef ITERK
}

// ---------------- kernel 3: flash attention, 32x32x16 MFMA, in-register P ----------------
// grid 768 blocks (swizzled), 256 thr = 4 waves. Wave w owns q rows w*32..+31, computes the
// FULL 128-kpos S^T tile for them (S^T = K·Q^T: lane's sacc col = its q row).
// P never touches LDS (sigma-permuted vt makes PV A-frags register-natural).
// T1 chunked XCD swizzle: 8 consecutive same-XCD blocks share one (b,h) K/V head.
// T5: setprio around both MFMA clusters.
__global__ __launch_bounds__(256, 3) void attn(const u16* __restrict__ qb, const u16* __restrict__ kb,
                                               const u16* __restrict__ vt, float* __restrict__ out) {
    __shared__ u16 Ks[128 * 64];   // K [kpos][64dh], chunk swz ^(r&7)
    __shared__ u16 Vs[64 * 128];   // V^T [dh][128 kappa], chunk swz ^(dh&15)
    __shared__ float Lw[128];
    // XCD swizzle: nwg=768, q=96, r=0 -> wg = (orig%8)*96 + orig/8 (bijective).
    int orig = blockIdx.x;
    int wg = (orig & 7) * 96 + (orig >> 3);
    int bh = wg >> 3;          // head index; 8 consecutive same-XCD blocks share it
    int q0 = (wg & 7) * 128;
    int b = bh / kH, h = bh % kH;
    int t = threadIdx.x, w = t >> 6, lane = t & 63;
    int l31 = lane & 31, hi = lane >> 5;
    int swz = l31 & 7;

    // Q register fragments (B operand: col=q=w*32+l31, k=dh): 4 frags cover dh 0..63
    bfx8 qf[4];
    {
        const u16* qrow = qb + (size_t)(b * kS + q0 + w * 32 + l31) * kD + h * kDH + hi * 8;
#pragma unroll
        for (int f = 0; f < 4; f++) qf[f] = *(const bfx8*)(qrow + f * 16);
    }

    float rsum = 0.f;
    floatx16 oacc[2] = {};

    for (int kt = 0; kt < 8; kt++) {
        int kk0 = kt * 128;
        __syncthreads();  // prev tile's K/V reads done before overwrite
        // stage K: 16 KB; wave w does jj=4w..4w+3; lane: row 8jj+(l>>3), phys chunk l&7
#pragma unroll
        for (int i = 0; i < 4; i++) {
            int jj = 4 * w + i;
            int r = 8 * jj + (lane >> 3);
            int c = (lane & 7) ^ ((lane >> 3) & 7);
            gld16(kb + (size_t)(b * kS + kk0 + r) * kD + h * kDH + c * 8, &Ks[jj * 512]);
        }
        // stage V^T: 16 KB; lane: row 4jj+(l>>4), phys chunk l&15
#pragma unroll
        for (int i = 0; i < 4; i++) {
            int jj = 4 * w + i;
            int r = 4 * jj + (lane >> 4);
            int c = (lane & 15) ^ (r & 15);
            gld16(vt + (((size_t)b * kH + h) * kDH + r) * kS + kk0 + c * 8, &Vs[jj * 512]);
        }
        __syncthreads();  // drain gld16 + publish

        // S^T: frag fm rows = kpos 32fm+l31, cols q = w*32+l31
        floatx16 sacc[4] = {};
        __builtin_amdgcn_s_setprio(1);
#pragma unroll
        for (int s2 = 0; s2 < 4; s2++) {
#pragma unroll
            for (int fm = 0; fm < 4; fm++) {
                bfx8 ak = *(const bfx8*)&Ks[(fm * 32 + l31) * 64 + ((s2 * 2 + hi) ^ swz) * 8];
                sacc[fm] = __builtin_amdgcn_mfma_f32_32x32x16_bf16(ak, qf[s2], sacc[fm], 0, 0, 0);
            }
        }
        __builtin_amdgcn_s_setprio(0);

        // exp + pack to PV A-fragments, fully in-register
        bfx8 pa[4][2];
#pragma unroll
        for (int fm = 0; fm < 4; fm++) {
#pragma unroll
            for (int hh = 0; hh < 2; hh++) {
                bfx8 pv;
#pragma unroll
                for (int jj = 0; jj < 8; jj++) {
                    float e = __expf(sacc[fm][8 * hh + jj]);
                    rsum += e;
                    pv[jj] = (__bf16)e;
                }
                pa[fm][hh] = pv;
            }
        }

        // O += P·V over sigma-space kappa: A = pa[s>>1][s&1], B = Vs rows dh = db*32+l31
        __builtin_amdgcn_s_setprio(1);
#pragma unroll
        for (int s = 0; s < 8; s++) {
#pragma unroll
            for (int db = 0; db < 2; db++) {
                bfx8 bv = *(const bfx8*)((const u8*)Vs + (db * 32 + l31) * 256 + (((s * 2 + hi) ^ (l31 & 15)) * 16));
                oacc[db] = __builtin_amdgcn_mfma_f32_32x32x16_bf16(pa[s >> 1][s & 1], bv, oacc[db], 0, 0, 0);
            }
        }
        __builtin_amdgcn_s_setprio(0);
    }

    // lane holds sum over kpos with bit2==4*hi for q=l31; fold partner across lane^32
    rsum += __shfl_xor(rsum, 32, 64);
    if (lane < 32) Lw[w * 32 + lane] = rsum;
    __syncthreads();
    // O: col = dh = db*32+l31, row = q = w*32 + (reg&3)+8*(reg>>2)+4*hi
#pragma unroll
    for (int g = 0; g < 4; g++) {
#pragma unroll
        for (int r2 = 0; r2 < 4; r2++) {
            int qloc = w * 32 + 4 * hi + r2 + 8 * g;
            float linv = 1.0f / Lw[qloc];
#pragma unroll
            for (int db = 0; db < 2; db++) {
                out[(size_t)(b * kS + q0 + qloc) * kD + h * kDH + db * 32 + l31] = oacc[db][4 * g + r2] * linv;
            }
        }
    }
}

extern "C" void kernel_launch(void* const* d_in, const int* in_sizes, int n_in,
                              void* d_out, int out_size, void* d_ws, size_t ws_size,
                              hipStream_t stream) {
    const float* x  = (const float*)d_in[0];
    const float* Wq = (const float*)d_in[1];
    const float* bq = (const float*)d_in[2];
    const float* Wk = (const float*)d_in[3];
    const float* bk = (const float*)d_in[4];
    const float* Wv = (const float*)d_in[5];
    const float* bv = (const float*)d_in[6];
    float* out = (float*)d_out;

    u16* ws = (u16*)d_ws;
    u16* xb = ws;                   // 8192*768
    u16* wt = xb + 6291456;         // 3*768*768 concat [2304][768]
    u16* qb = wt + 1769472;         // scaled Q bf16
    u16* kb = qb + 6291456;
    u16* vt = kb + 6291456;         // V^T per head (b,h,dh,s), s sigma-permuted (bits 2<->3)

    cvt<<<dim3(7872), dim3(256), 0, stream>>>(x, xb, Wq, Wk, Wv, wt);
    proj<<<dim3(288), dim3(512), 0, stream>>>(xb, wt, bq, bk, bv, qb, kb, vt);
    attn<<<dim3(768), dim3(256), 0, stream>>>(qb, kb, vt, out);
}

// Round 5
// 172.052 us; speedup vs baseline: 1.0398x; 1.0398x over previous
//
#include <hip/hip_runtime.h>
#include <cstdint>
#include <cstddef>

typedef unsigned short u16;
typedef unsigned int u32;
typedef unsigned char u8;

using bfx8 = __attribute__((ext_vector_type(8))) __bf16;
using floatx16 = __attribute__((ext_vector_type(16))) float;

// B=8, S=1024, D=768, H=12, DH=64
static constexpr int kS = 1024;
static constexpr int kD = 768;
static constexpr int kH = 12;
static constexpr int kDH = 64;
#define SCALE 0.036084391824351614f  // 1/sqrt(768)

__device__ __forceinline__ u16 f2bf(float f) {
    u32 u = __float_as_uint(f);
    return (u16)((u + 0x7fffu + ((u >> 16) & 1u)) >> 16);
}

// async global->LDS, 16B per lane. LDS dst = uniform base + lane*16.
__device__ __forceinline__ void gld16(const void* g, void* l) {
    __builtin_amdgcn_global_load_lds(
        (__attribute__((address_space(1))) const u32*)g,
        (__attribute__((address_space(3))) u32*)l, 16, 0, 0);
}

// ---------------- kernel 1: fused converts ----------------
// blocks [0,6144): x fp32 -> bf16.  blocks [6144,7872): W (k,n) fp32 -> Wt (n,k) bf16 concat.
__global__ __launch_bounds__(256) void cvt(const float* __restrict__ x, u16* __restrict__ xb,
                                           const float* __restrict__ w0, const float* __restrict__ w1,
                                           const float* __restrict__ w2, u16* __restrict__ wt) {
    __shared__ float t[32][33];
    int bid = blockIdx.x;
    if (bid < 6144) {
        int i = (bid * 256 + threadIdx.x) * 4;
        float4 v = *(const float4*)(x + i);
        u32 lo = (u32)f2bf(v.x) | ((u32)f2bf(v.y) << 16);
        u32 hi = (u32)f2bf(v.z) | ((u32)f2bf(v.w) << 16);
        *(uint2*)(xb + i) = make_uint2(lo, hi);
    } else {
        int idx = bid - 6144;
        int z = idx / 576;
        int rem = idx - z * 576;
        int by = rem / 24, bx = rem - by * 24;
        const float* W = z == 0 ? w0 : (z == 1 ? w1 : w2);
        u16* dst = wt + (size_t)z * kD * kD;
        int k0 = bx * 32, n0 = by * 32;
        int tx = threadIdx.x & 31, ty = threadIdx.x >> 5;  // 32 x 8
#pragma unroll
        for (int j = 0; j < 4; j++)
            t[ty + j * 8][tx] = W[(size_t)(k0 + ty + j * 8) * kD + n0 + tx];
        __syncthreads();
#pragma unroll
        for (int j = 0; j < 4; j++)
            dst[(size_t)(n0 + ty + j * 8) * kD + k0 + tx] = f2bf(t[tx][ty + j * 8]);
    }
}

// ---------------- kernel 2: fused QKV projection GEMM (32x32x16 MFMA) ----------------
// EXACT revert to the R2 version (measured 48.6 us): 128x128 tile, 4 waves, T3-minimum
// 2-phase double-buffered LDS, stage(next) before compute(cur), 1 barrier per K-step.
// (R3's 256x256 8-phase regressed: 1 block/CU x 288 blocks = 2 occupancy rounds.)
__global__ __launch_bounds__(256) void proj(const u16* __restrict__ xb, const u16* __restrict__ wt,
                                            const float* __restrict__ bq, const float* __restrict__ bk,
                                            const float* __restrict__ bvp,
                                            u16* __restrict__ qb, u16* __restrict__ kb, u16* __restrict__ vt) {
    __shared__ u16 As0[128 * 64];
    __shared__ u16 Bs0[128 * 64];
    __shared__ u16 As1[128 * 64];
    __shared__ u16 Bs1[128 * 64];
    // XCD swizzle: nwg=1152, 8 XCDs, q=144, r=0 -> wg = (orig%8)*144 + orig/8 (bijective).
    int orig = blockIdx.x;
    int wg = (orig & 7) * 144 + (orig >> 3);
    int mt = wg / 18, nt = wg - mt * 18;   // n-fastest within each XCD chunk
    int m0 = mt * 128;
    int n0g = nt * 128;
    int t = threadIdx.x;
    int w = t >> 6, lane = t & 63;
    int l31 = lane & 31, hi = lane >> 5;
    int wm = (w & 1) * 64, wn = (w >> 1) * 64;
    int rloc8 = lane >> 3, p8 = lane & 7;
    int chw = p8 ^ rloc8;  // global-side logical chunk for this lane's phys slot
    const u16* Brow = wt + (size_t)n0g * kD;
    int swz = l31 & 7;
    floatx16 acc[2][2] = {};

    auto STAGE = [&](u16* Ad, u16* Bd, int ks) {
#pragma unroll
        for (int i = 0; i < 4; i++) {
            int j = w * 4 + i;
            int r = 8 * j + rloc8;
            gld16(xb + (size_t)(m0 + r) * kD + ks + chw * 8, Ad + j * 512);
            gld16(Brow + (size_t)r * kD + ks + chw * 8, Bd + j * 512);
        }
    };
    auto COMP = [&](const u16* Ad, const u16* Bd) {
#pragma unroll
        for (int s = 0; s < 4; s++) {
            int tc = ((s * 2 + hi) ^ swz) * 8;
            bfx8 a[2], bf[2];
#pragma unroll
            for (int i = 0; i < 2; i++) {
                a[i] = *(const bfx8*)&Ad[(wm + i * 32 + l31) * 64 + tc];
                bf[i] = *(const bfx8*)&Bd[(wn + i * 32 + l31) * 64 + tc];
            }
#pragma unroll
            for (int i = 0; i < 2; i++)
#pragma unroll
                for (int j2 = 0; j2 < 2; j2++)
                    acc[i][j2] = __builtin_amdgcn_mfma_f32_32x32x16_bf16(a[i], bf[j2], acc[i][j2], 0, 0, 0);
        }
    };

    // prologue: stage ks=0 into buffer 0
    STAGE(As0, Bs0, 0);
    __syncthreads();
    // 5 unrolled-by-2 pairs: stages 64..640, computes 0..576
    for (int kk = 0; kk < 5; kk++) {
        STAGE(As1, Bs1, 64 + 128 * kk);
        COMP(As0, Bs0);
        __syncthreads();
        STAGE(As0, Bs0, 128 + 128 * kk);
        COMP(As1, Bs1);
        __syncthreads();
    }
    STAGE(As1, Bs1, 704);
    COMP(As0, Bs0);
    __syncthreads();
    COMP(As1, Bs1);

    // epilogue: C/D layout col=lane&31, row=(reg&3)+8*(reg>>2)+4*(lane>>5)
    int zz = nt / 6;                  // 0=Q 1=K 2=V
    int nl0 = (nt - zz * 6) * 128;
    const float* bias = zz == 0 ? bq : (zz == 1 ? bk : bvp);
    float mul = zz == 0 ? SCALE : 1.0f;
#pragma unroll
    for (int j = 0; j < 2; j++) {
        int nl = nl0 + wn + j * 32 + l31;
        float bb = bias[nl];
#pragma unroll
        for (int i = 0; i < 2; i++) {
            int mbase = m0 + wm + i * 32 + 4 * hi;
            if (zz < 2) {
                u16* dst = zz == 0 ? qb : kb;
#pragma unroll
                for (int reg = 0; reg < 16; reg++) {
                    int m = mbase + (reg & 3) + 8 * (reg >> 2);
                    dst[(size_t)m * kD + nl] = f2bf((acc[i][j][reg] + bb) * mul);
                }
            } else {
                int hh = nl >> 6, dh = nl & 63;
#pragma unroll
                for (int g = 0; g < 4; g++) {
                    // sigma-permuted store: original s had bit2=hi, bit3=g&1; swap them.
                    int m = (m0 + wm + i * 32) + 4 * (g & 1) + 8 * hi + 16 * (g >> 1);
                    int bi = m >> 10, s = m & 1023;
                    u32 lo = (u32)f2bf(acc[i][j][4 * g + 0] + bb) | ((u32)f2bf(acc[i][j][4 * g + 1] + bb) << 16);
                    u32 h2 = (u32)f2bf(acc[i][j][4 * g + 2] + bb) | ((u32)f2bf(acc[i][j][4 * g + 3] + bb) << 16);
                    *(uint2*)&vt[(((size_t)bi * kH + hh) * kDH + dh) * kS + s] = make_uint2(lo, h2);
                }
            }
        }
    }
}

// ---------------- kernel 3: flash attention, 32x32x16 MFMA, in-register P, 2-phase ----------------
// grid 768 blocks (swizzled), 256 thr = 4 waves. Wave w owns q rows w*32..+31, computes the
// FULL 128-kpos S^T tile for them (S^T = K·Q^T: lane's sacc col = its q row).
// P never touches LDS (sigma-permuted vt makes PV A-frags register-natural).
// T3-minimum 2-phase: K/V double-buffered; STAGE(kt+1) issued BEFORE compute(kt);
// ONE barrier per tile (implicit vmcnt-0 drain at the end-of-iteration __syncthreads) --
// stage latency hides under 32 MFMA + 32 expf of the current tile.
__global__ __launch_bounds__(256, 2) void attn(const u16* __restrict__ qb, const u16* __restrict__ kb,
                                               const u16* __restrict__ vt, float* __restrict__ out) {
    __shared__ u16 Ks[2][128 * 64];   // K [kpos][64dh], chunk swz ^(r&7)
    __shared__ u16 Vs[2][64 * 128];   // V^T [dh][128 kappa], chunk swz ^(dh&15)
    __shared__ float Lw[128];
    // XCD swizzle: nwg=768, q=96, r=0 -> wg = (orig%8)*96 + orig/8 (bijective).
    int orig = blockIdx.x;
    int wg = (orig & 7) * 96 + (orig >> 3);
    int bh = wg >> 3;          // head index; 8 consecutive same-XCD blocks share it
    int q0 = (wg & 7) * 128;
    int b = bh / kH, h = bh % kH;
    int t = threadIdx.x, w = t >> 6, lane = t & 63;
    int l31 = lane & 31, hi = lane >> 5;
    int swz = l31 & 7;

    // Q register fragments (B operand: col=q=w*32+l31, k=dh): 4 frags cover dh 0..63
    bfx8 qf[4];
    {
        const u16* qrow = qb + (size_t)(b * kS + q0 + w * 32 + l31) * kD + h * kDH + hi * 8;
#pragma unroll
        for (int f = 0; f < 4; f++) qf[f] = *(const bfx8*)(qrow + f * 16);
    }

    auto STAGE = [&](int db, int kt) {
        int kk0 = kt * 128;
        // K: 16 KB; wave w does jj=4w..4w+3; lane: row 8jj+(l>>3), phys chunk l&7
#pragma unroll
        for (int i = 0; i < 4; i++) {
            int jj = 4 * w + i;
            int r = 8 * jj + (lane >> 3);
            int c = (lane & 7) ^ ((lane >> 3) & 7);
            gld16(kb + (size_t)(b * kS + kk0 + r) * kD + h * kDH + c * 8, &Ks[db][jj * 512]);
        }
        // V^T: 16 KB; lane: row 4jj+(l>>4), phys chunk l&15
#pragma unroll
        for (int i = 0; i < 4; i++) {
            int jj = 4 * w + i;
            int r = 4 * jj + (lane >> 4);
            int c = (lane & 15) ^ (r & 15);
            gld16(vt + (((size_t)b * kH + h) * kDH + r) * kS + kk0 + c * 8, &Vs[db][jj * 512]);
        }
    };

    float rsum = 0.f;
    floatx16 oacc[2] = {};

    // prologue: stage tile 0, drain+publish
    STAGE(0, 0);
    __syncthreads();

    int cur = 0;
    for (int kt = 0; kt < 8; kt++) {
        if (kt < 7) STAGE(cur ^ 1, kt + 1);  // issue next tile's loads (other buffer)

        // S^T: frag fm rows = kpos 32fm+l31, cols q = w*32+l31
        const u16* Kc = Ks[cur];
        const u8* Vc = (const u8*)Vs[cur];
        floatx16 sacc[4] = {};
        __builtin_amdgcn_s_setprio(1);
#pragma unroll
        for (int s2 = 0; s2 < 4; s2++) {
#pragma unroll
            for (int fm = 0; fm < 4; fm++) {
                bfx8 ak = *(const bfx8*)&Kc[(fm * 32 + l31) * 64 + ((s2 * 2 + hi) ^ swz) * 8];
                sacc[fm] = __builtin_amdgcn_mfma_f32_32x32x16_bf16(ak, qf[s2], sacc[fm], 0, 0, 0);
            }
        }
        __builtin_amdgcn_s_setprio(0);

        // exp + pack to PV A-fragments, fully in-register
        bfx8 pa[4][2];
#pragma unroll
        for (int fm = 0; fm < 4; fm++) {
#pragma unroll
            for (int hh = 0; hh < 2; hh++) {
                bfx8 pv;
#pragma unroll
                for (int jj = 0; jj < 8; jj++) {
                    float e = __expf(sacc[fm][8 * hh + jj]);
                    rsum += e;
                    pv[jj] = (__bf16)e;
                }
                pa[fm][hh] = pv;
            }
        }

        // O += P·V over sigma-space kappa: A = pa[s>>1][s&1], B = Vs rows dh = db*32+l31
        __builtin_amdgcn_s_setprio(1);
#pragma unroll
        for (int s = 0; s < 8; s++) {
#pragma unroll
            for (int db = 0; db < 2; db++) {
                bfx8 bv = *(const bfx8*)(Vc + (db * 32 + l31) * 256 + (((s * 2 + hi) ^ (l31 & 15)) * 16));
                oacc[db] = __builtin_amdgcn_mfma_f32_32x32x16_bf16(pa[s >> 1][s & 1], bv, oacc[db], 0, 0, 0);
            }
        }
        __builtin_amdgcn_s_setprio(0);

        __syncthreads();  // drain next-tile gld16 + guard cur-buffer overwrite next iter
        cur ^= 1;
    }

    // lane holds sum over kpos with bit2==4*hi for q=l31; fold partner across lane^32
    rsum += __shfl_xor(rsum, 32, 64);
    if (lane < 32) Lw[w * 32 + lane] = rsum;
    __syncthreads();
    // O: col = dh = db*32+l31, row = q = w*32 + (reg&3)+8*(reg>>2)+4*hi
#pragma unroll
    for (int g = 0; g < 4; g++) {
#pragma unroll
        for (int r2 = 0; r2 < 4; r2++) {
            int qloc = w * 32 + 4 * hi + r2 + 8 * g;
            float linv = 1.0f / Lw[qloc];
#pragma unroll
            for (int db = 0; db < 2; db++) {
                out[(size_t)(b * kS + q0 + qloc) * kD + h * kDH + db * 32 + l31] = oacc[db][4 * g + r2] * linv;
            }
        }
    }
}

extern "C" void kernel_launch(void* const* d_in, const int* in_sizes, int n_in,
                              void* d_out, int out_size, void* d_ws, size_t ws_size,
                              hipStream_t stream) {
    const float* x  = (const float*)d_in[0];
    const float* Wq = (const float*)d_in[1];
    const float* bq = (const float*)d_in[2];
    const float* Wk = (const float*)d_in[3];
    const float* bk = (const float*)d_in[4];
    const float* Wv = (const float*)d_in[5];
    const float* bv = (const float*)d_in[6];
    float* out = (float*)d_out;

    u16* ws = (u16*)d_ws;
    u16* xb = ws;                   // 8192*768
    u16* wt = xb + 6291456;         // 3*768*768 concat [2304][768]
    u16* qb = wt + 1769472;         // scaled Q bf16
    u16* kb = qb + 6291456;
    u16* vt = kb + 6291456;         // V^T per head (b,h,dh,s), s sigma-permuted (bits 2<->3)

    cvt<<<dim3(7872), dim3(256), 0, stream>>>(x, xb, Wq, Wk, Wv, wt);
    proj<<<dim3(1152), dim3(256), 0, stream>>>(xb, wt, bq, bk, bv, qb, kb, vt);
    attn<<<dim3(768), dim3(256), 0, stream>>>(qb, kb, vt, out);
}

// Round 6
// 166.445 us; speedup vs baseline: 1.0748x; 1.0337x over previous
//
#include <hip/hip_runtime.h>
#include <cstdint>
#include <cstddef>

typedef unsigned short u16;
typedef unsigned int u32;
typedef unsigned char u8;

using bfx8 = __attribute__((ext_vector_type(8))) __bf16;
using floatx16 = __attribute__((ext_vector_type(16))) float;

// B=8, S=1024, D=768, H=12, DH=64
static constexpr int kS = 1024;
static constexpr int kD = 768;
static constexpr int kH = 12;
static constexpr int kDH = 64;
#define SCALE 0.036084391824351614f  // 1/sqrt(768)

__device__ __forceinline__ u16 f2bf(float f) {
    u32 u = __float_as_uint(f);
    return (u16)((u + 0x7fffu + ((u >> 16) & 1u)) >> 16);
}

// async global->LDS, 16B per lane. LDS dst = uniform base + lane*16.
__device__ __forceinline__ void gld16(const void* g, void* l) {
    __builtin_amdgcn_global_load_lds(
        (__attribute__((address_space(1))) const u32*)g,
        (__attribute__((address_space(3))) u32*)l, 16, 0, 0);
}

// ---------------- kernel 1: fused converts ----------------
// blocks [0,6144): x fp32 -> bf16.  blocks [6144,7872): W (k,n) fp32 -> Wt (n,k) bf16 concat.
__global__ __launch_bounds__(256) void cvt(const float* __restrict__ x, u16* __restrict__ xb,
                                           const float* __restrict__ w0, const float* __restrict__ w1,
                                           const float* __restrict__ w2, u16* __restrict__ wt) {
    __shared__ float t[32][33];
    int bid = blockIdx.x;
    if (bid < 6144) {
        int i = (bid * 256 + threadIdx.x) * 4;
        float4 v = *(const float4*)(x + i);
        u32 lo = (u32)f2bf(v.x) | ((u32)f2bf(v.y) << 16);
        u32 hi = (u32)f2bf(v.z) | ((u32)f2bf(v.w) << 16);
        *(uint2*)(xb + i) = make_uint2(lo, hi);
    } else {
        int idx = bid - 6144;
        int z = idx / 576;
        int rem = idx - z * 576;
        int by = rem / 24, bx = rem - by * 24;
        const float* W = z == 0 ? w0 : (z == 1 ? w1 : w2);
        u16* dst = wt + (size_t)z * kD * kD;
        int k0 = bx * 32, n0 = by * 32;
        int tx = threadIdx.x & 31, ty = threadIdx.x >> 5;  // 32 x 8
#pragma unroll
        for (int j = 0; j < 4; j++)
            t[ty + j * 8][tx] = W[(size_t)(k0 + ty + j * 8) * kD + n0 + tx];
        __syncthreads();
#pragma unroll
        for (int j = 0; j < 4; j++)
            dst[(size_t)(n0 + ty + j * 8) * kD + k0 + tx] = f2bf(t[tx][ty + j * 8]);
    }
}

// ---------------- kernel 2: fused QKV projection GEMM (32x32x16 MFMA) ----------------
// R2 version (measured 48.6 us): 128x128 tile, 4 waves, T3-minimum 2-phase double-buffered
// LDS, stage(next) before compute(cur), 1 barrier per K-step. UNCHANGED this round.
__global__ __launch_bounds__(256) void proj(const u16* __restrict__ xb, const u16* __restrict__ wt,
                                            const float* __restrict__ bq, const float* __restrict__ bk,
                                            const float* __restrict__ bvp,
                                            u16* __restrict__ qb, u16* __restrict__ kb, u16* __restrict__ vt) {
    __shared__ u16 As0[128 * 64];
    __shared__ u16 Bs0[128 * 64];
    __shared__ u16 As1[128 * 64];
    __shared__ u16 Bs1[128 * 64];
    // XCD swizzle: nwg=1152, 8 XCDs, q=144, r=0 -> wg = (orig%8)*144 + orig/8 (bijective).
    int orig = blockIdx.x;
    int wg = (orig & 7) * 144 + (orig >> 3);
    int mt = wg / 18, nt = wg - mt * 18;   // n-fastest within each XCD chunk
    int m0 = mt * 128;
    int n0g = nt * 128;
    int t = threadIdx.x;
    int w = t >> 6, lane = t & 63;
    int l31 = lane & 31, hi = lane >> 5;
    int wm = (w & 1) * 64, wn = (w >> 1) * 64;
    int rloc8 = lane >> 3, p8 = lane & 7;
    int chw = p8 ^ rloc8;  // global-side logical chunk for this lane's phys slot
    const u16* Brow = wt + (size_t)n0g * kD;
    int swz = l31 & 7;
    floatx16 acc[2][2] = {};

    auto STAGE = [&](u16* Ad, u16* Bd, int ks) {
#pragma unroll
        for (int i = 0; i < 4; i++) {
            int j = w * 4 + i;
            int r = 8 * j + rloc8;
            gld16(xb + (size_t)(m0 + r) * kD + ks + chw * 8, Ad + j * 512);
            gld16(Brow + (size_t)r * kD + ks + chw * 8, Bd + j * 512);
        }
    };
    auto COMP = [&](const u16* Ad, const u16* Bd) {
#pragma unroll
        for (int s = 0; s < 4; s++) {
            int tc = ((s * 2 + hi) ^ swz) * 8;
            bfx8 a[2], bf[2];
#pragma unroll
            for (int i = 0; i < 2; i++) {
                a[i] = *(const bfx8*)&Ad[(wm + i * 32 + l31) * 64 + tc];
                bf[i] = *(const bfx8*)&Bd[(wn + i * 32 + l31) * 64 + tc];
            }
#pragma unroll
            for (int i = 0; i < 2; i++)
#pragma unroll
                for (int j2 = 0; j2 < 2; j2++)
                    acc[i][j2] = __builtin_amdgcn_mfma_f32_32x32x16_bf16(a[i], bf[j2], acc[i][j2], 0, 0, 0);
        }
    };

    // prologue: stage ks=0 into buffer 0
    STAGE(As0, Bs0, 0);
    __syncthreads();
    // 5 unrolled-by-2 pairs: stages 64..640, computes 0..576
    for (int kk = 0; kk < 5; kk++) {
        STAGE(As1, Bs1, 64 + 128 * kk);
        COMP(As0, Bs0);
        __syncthreads();
        STAGE(As0, Bs0, 128 + 128 * kk);
        COMP(As1, Bs1);
        __syncthreads();
    }
    STAGE(As1, Bs1, 704);
    COMP(As0, Bs0);
    __syncthreads();
    COMP(As1, Bs1);

    // epilogue: C/D layout col=lane&31, row=(reg&3)+8*(reg>>2)+4*(lane>>5)
    int zz = nt / 6;                  // 0=Q 1=K 2=V
    int nl0 = (nt - zz * 6) * 128;
    const float* bias = zz == 0 ? bq : (zz == 1 ? bk : bvp);
    float mul = zz == 0 ? SCALE : 1.0f;
#pragma unroll
    for (int j = 0; j < 2; j++) {
        int nl = nl0 + wn + j * 32 + l31;
        float bb = bias[nl];
#pragma unroll
        for (int i = 0; i < 2; i++) {
            int mbase = m0 + wm + i * 32 + 4 * hi;
            if (zz < 2) {
                u16* dst = zz == 0 ? qb : kb;
#pragma unroll
                for (int reg = 0; reg < 16; reg++) {
                    int m = mbase + (reg & 3) + 8 * (reg >> 2);
                    dst[(size_t)m * kD + nl] = f2bf((acc[i][j][reg] + bb) * mul);
                }
            } else {
                int hh = nl >> 6, dh = nl & 63;
#pragma unroll
                for (int g = 0; g < 4; g++) {
                    // sigma-permuted store: original s had bit2=hi, bit3=g&1; swap them.
                    int m = (m0 + wm + i * 32) + 4 * (g & 1) + 8 * hi + 16 * (g >> 1);
                    int bi = m >> 10, s = m & 1023;
                    u32 lo = (u32)f2bf(acc[i][j][4 * g + 0] + bb) | ((u32)f2bf(acc[i][j][4 * g + 1] + bb) << 16);
                    u32 h2 = (u32)f2bf(acc[i][j][4 * g + 2] + bb) | ((u32)f2bf(acc[i][j][4 * g + 3] + bb) << 16);
                    *(uint2*)&vt[(((size_t)bi * kH + hh) * kDH + dh) * kS + s] = make_uint2(lo, h2);
                }
            }
        }
    }
}

// ---------------- kernel 3: flash attention, KVBLK=64, double-buffered, in-register P ----------------
// grid 768 blocks (swizzled), 256 thr = 4 waves. Wave w owns q rows w*32..+31 and the FULL
// 64-kpos S^T tile for them (S^T = K·Q^T). 16 K/V tiles of 64 kpos, double-buffered:
// STAGE(kt+1) issued before compute(kt), ONE barrier per tile. LDS = 32.5 KiB -> 3 blocks/CU
// co-resident (768 = 256 CUs x 3, single occupancy round — the R4/R5 128-kpos dbuf broke this).
// P never touches LDS (sigma-permuted vt: PV instr s A-frag = pa[s>>1][s&1], derivation
// unchanged — sigma only touches kappa bits 2,3).
__global__ __launch_bounds__(256, 3) void attn(const u16* __restrict__ qb, const u16* __restrict__ kb,
                                               const u16* __restrict__ vt, float* __restrict__ out) {
    __shared__ u16 Ks[2][64 * 64];   // K [kpos][64dh], chunk swz ^(r&7)
    __shared__ u16 Vs[2][64 * 64];   // V^T [dh][64 kappa], chunk swz ^(dh&7)
    __shared__ float Lw[128];
    // XCD swizzle: nwg=768, q=96, r=0 -> wg = (orig%8)*96 + orig/8 (bijective).
    int orig = blockIdx.x;
    int wg = (orig & 7) * 96 + (orig >> 3);
    int bh = wg >> 3;          // head index; 8 consecutive same-XCD blocks share it
    int q0 = (wg & 7) * 128;
    int b = bh / kH, h = bh % kH;
    int t = threadIdx.x, w = t >> 6, lane = t & 63;
    int l31 = lane & 31, hi = lane >> 5;
    int swz = l31 & 7;

    // Q register fragments (B operand: col=q=w*32+l31, k=dh): 4 frags cover dh 0..63
    bfx8 qf[4];
    {
        const u16* qrow = qb + (size_t)(b * kS + q0 + w * 32 + l31) * kD + h * kDH + hi * 8;
#pragma unroll
        for (int f = 0; f < 4; f++) qf[f] = *(const bfx8*)(qrow + f * 16);
    }

    // stage one 64-kpos tile (K 8KB + V 8KB); wave w does units jj=2w,2w+1 of each
    auto STAGE = [&](int db, int kt) {
        int kk0 = kt * 64;
#pragma unroll
        for (int i = 0; i < 2; i++) {
            int jj = 2 * w + i;
            int r = 8 * jj + (lane >> 3);
            int c = (lane & 7) ^ ((lane >> 3) & 7);
            gld16(kb + (size_t)(b * kS + kk0 + r) * kD + h * kDH + c * 8, &Ks[db][jj * 512]);
        }
#pragma unroll
        for (int i = 0; i < 2; i++) {
            int jj = 2 * w + i;
            int r = 8 * jj + (lane >> 3);   // dh row
            int c = (lane & 7) ^ ((lane >> 3) & 7);
            gld16(vt + (((size_t)b * kH + h) * kDH + r) * kS + kk0 + c * 8, &Vs[db][jj * 512]);
        }
    };

    float rsum = 0.f;
    floatx16 oacc[2] = {};

    // prologue: stage tile 0, drain+publish
    STAGE(0, 0);
    __syncthreads();

    int cur = 0;
    for (int kt = 0; kt < 16; kt++) {
        if (kt < 15) STAGE(cur ^ 1, kt + 1);  // issue next tile's loads (other buffer)

        const u16* Kc = Ks[cur];
        const u8* Vc = (const u8*)Vs[cur];

        // S^T: frag fm rows = kpos 32fm+l31 (local), cols q = w*32+l31
        floatx16 sacc[2] = {};
        __builtin_amdgcn_s_setprio(1);
#pragma unroll
        for (int s2 = 0; s2 < 4; s2++) {
#pragma unroll
            for (int fm = 0; fm < 2; fm++) {
                bfx8 ak = *(const bfx8*)&Kc[(fm * 32 + l31) * 64 + ((s2 * 2 + hi) ^ swz) * 8];
                sacc[fm] = __builtin_amdgcn_mfma_f32_32x32x16_bf16(ak, qf[s2], sacc[fm], 0, 0, 0);
            }
        }
        __builtin_amdgcn_s_setprio(0);

        // exp + pack to PV A-fragments, fully in-register
        bfx8 pa[2][2];
#pragma unroll
        for (int fm = 0; fm < 2; fm++) {
#pragma unroll
            for (int hh = 0; hh < 2; hh++) {
                bfx8 pv;
#pragma unroll
                for (int jj = 0; jj < 8; jj++) {
                    float e = __expf(sacc[fm][8 * hh + jj]);
                    rsum += e;
                    pv[jj] = (__bf16)e;
                }
                pa[fm][hh] = pv;
            }
        }

        // O += P·V over sigma-space kappa: A = pa[s>>1][s&1], B = Vs rows dh = db*32+l31
        __builtin_amdgcn_s_setprio(1);
#pragma unroll
        for (int s = 0; s < 4; s++) {
#pragma unroll
            for (int db = 0; db < 2; db++) {
                bfx8 bv = *(const bfx8*)(Vc + (db * 32 + l31) * 128 + (((s * 2 + hi) ^ swz) * 16));
                oacc[db] = __builtin_amdgcn_mfma_f32_32x32x16_bf16(pa[s >> 1][s & 1], bv, oacc[db], 0, 0, 0);
            }
        }
        __builtin_amdgcn_s_setprio(0);

        __syncthreads();  // drain next-tile gld16 + guard cur-buffer overwrite next iter
        cur ^= 1;
    }

    // lane holds sum over kpos with bit2==4*hi for q=l31; fold partner across lane^32
    rsum += __shfl_xor(rsum, 32, 64);
    if (lane < 32) Lw[w * 32 + lane] = rsum;
    __syncthreads();
    // O: col = dh = db*32+l31, row = q = w*32 + (reg&3)+8*(reg>>2)+4*hi
#pragma unroll
    for (int g = 0; g < 4; g++) {
#pragma unroll
        for (int r2 = 0; r2 < 4; r2++) {
            int qloc = w * 32 + 4 * hi + r2 + 8 * g;
            float linv = 1.0f / Lw[qloc];
#pragma unroll
            for (int db = 0; db < 2; db++) {
                out[(size_t)(b * kS + q0 + qloc) * kD + h * kDH + db * 32 + l31] = oacc[db][4 * g + r2] * linv;
            }
        }
    }
}

extern "C" void kernel_launch(void* const* d_in, const int* in_sizes, int n_in,
                              void* d_out, int out_size, void* d_ws, size_t ws_size,
                              hipStream_t stream) {
    const float* x  = (const float*)d_in[0];
    const float* Wq = (const float*)d_in[1];
    const float* bq = (const float*)d_in[2];
    const float* Wk = (const float*)d_in[3];
    const float* bk = (const float*)d_in[4];
    const float* Wv = (const float*)d_in[5];
    const float* bv = (const float*)d_in[6];
    float* out = (float*)d_out;

    u16* ws = (u16*)d_ws;
    u16* xb = ws;                   // 8192*768
    u16* wt = xb + 6291456;         // 3*768*768 concat [2304][768]
    u16* qb = wt + 1769472;         // scaled Q bf16
    u16* kb = qb + 6291456;
    u16* vt = kb + 6291456;         // V^T per head (b,h,dh,s), s sigma-permuted (bits 2<->3)

    cvt<<<dim3(7872), dim3(256), 0, stream>>>(x, xb, Wq, Wk, Wv, wt);
    proj<<<dim3(1152), dim3(256), 0, stream>>>(xb, wt, bq, bk, bv, qb, kb, vt);
    attn<<<dim3(768), dim3(256), 0, stream>>>(qb, kb, vt, out);
}